// Round 11
// baseline (180.679 us; speedup 1.0000x reference)
//
#include <hip/hip_runtime.h>

// One-level separable wavelet filterbank (maxflat), periodic extension.
// x: [8,3,1024,1024] f32 -> out: [4, 8,3,512,512] f32 (LL, LH, HL, HH)
//
// Round 13: persistent blocks + double-buffered global_load_lds pipeline
// with COUNTED vmcnt waits and raw s_barrier (T3/T4). Round-12 showed
// conflicts fixed (22.5M -> 1M) but time flat at ~60us: the __syncthreads
// vmcnt(0) drain serializes load latency with compute every tile. Here
// each block walks YT=8 y-tiles: while tile t computes from buf[t&1],
// tile t+2's loads fly into buf[(t+1)&1]; the inter-tile barrier waits
// only vmcnt(9) (= 5 next-tile loads + 4 prev stores, per-wave ledger,
// in-order retirement per m135), never 0. 43KB LDS -> 3 blocks/CU with
// 3x21KB permanently in flight -> HBM-bound steady state.

constexpr int H = 1024, W = 1024;
constexpr int NIMG = 24;            // 8*3
constexpr int HOUT = 512, WOUT = 512;
constexpr int BROWS = 16;           // output rows per tile (tid>>4)
constexpr int BCOLS = 64;           // output cols per block (16 groups of 4)
constexpr int YT    = 8;            // y-tiles per block (persistent walk)
constexpr int TROWS = 37;           // staged input rows per tile
constexpr int TSEGS = 36;           // 16B segs per staged row (34 used)
constexpr int NSEG  = TROWS * TSEGS;          // 1332
constexpr int NCHUNK = (NSEG + 63) / 64;      // 21 chunks (1KB wave loads)
constexpr int ROWF  = TSEGS * 4;              // 144 floats per LDS row
constexpr int BUFF  = NCHUNK * 256;           // 5376 floats per buffer

__global__ __launch_bounds__(256)
void wfb_kernel(const float* __restrict__ x, float* __restrict__ out) {
    __shared__ __align__(16) float smem[2][BUFF];   // 43008 B -> 3 blocks/CU

    // h (len 5, ext 2) and h1 (len 7, ext 4), exact maxflat values
    const float h0c[5] = {0.125f, 0.35355339059327373f, 1.25f,
                          0.35355339059327373f, 0.125f};
    const float h1c[7] = {0.025888347648318447f,  0.07322330470336313f,
                          -0.06878156646177083f, -0.8535533905932737f,
                          -0.06878156646177083f,  0.07322330470336313f,
                          0.025888347648318447f};

    const int tid  = threadIdx.x;
    const int wave = tid >> 6;          // 0..3 (wave0 carries 6 chunks, rest 5)
    const int lane = tid & 63;
    const int img  = blockIdx.z;
    const int R0b  = blockIdx.y * (YT * BROWS);   // block's first output row
    const int J0b  = blockIdx.x * BCOLS;
    const float* __restrict__ xin = x + (size_t)img * H * W;
    const int cb0 = 2 * J0b - 4;        // first staged col; %4==0 -> 16B align

    // stage tile t into buffer b: source pre-swizzled (seg s_lds holds
    // global seg s_lds ^ e(r), e(r)=(r>>1)&1), LDS dest linear (HW rule).
    auto STAGE = [&](int t, int b) {
        const int rb0 = 2 * (R0b + t * BROWS) - 4;
        for (int c = wave; c < NCHUNK; c += 4) {
            int u  = c * 64 + lane;
            int r  = u / TSEGS;
            int s  = u - r * TSEGS;
            int e  = (r >> 1) & 1;
            int gr = (rb0 + r) & (H - 1);            // periodic rows
            int gc = (cb0 + 4 * (s ^ e)) & (W - 1);  // periodic, 16B kept
            const float* gp = xin + ((size_t)gr << 10) + gc;
            __builtin_amdgcn_global_load_lds(
                (const __attribute__((address_space(1))) void*)gp,
                (__attribute__((address_space(3))) void*)(&smem[b][c * 256]),
                16, 0, 0);
        }
    };

    const int Rl = tid >> 4;            // 0..15 output row in tile
    const int s0 = (tid & 15) * 2;      // first logical seg (even)
    constexpr size_t SB = (size_t)NIMG * HOUT * WOUT;
    float* __restrict__ o = out + (size_t)img * HOUT * WOUT;

    STAGE(0, 0);                        // prologue: two tiles in flight
    STAGE(1, 1);

    #pragma unroll
    for (int t = 0; t < YT; ++t) {
        // counted wait: own tile-t loads landed (ledger: loads precede
        // stores each iter; vmcnt retires in order). NEVER vmcnt(0).
        if (t == 0)           asm volatile("s_waitcnt vmcnt(5)" ::: "memory");
        else if (t == YT - 1) asm volatile("s_waitcnt vmcnt(4)" ::: "memory");
        else                  asm volatile("s_waitcnt vmcnt(9)" ::: "memory");
        __builtin_amdgcn_s_barrier();              // whole tile t visible
        __builtin_amdgcn_sched_barrier(0);

        const float* __restrict__ bufc = smem[t & 1];
        float vA[13], vB[13];
        #pragma unroll
        for (int c = 0; c < 13; ++c) { vA[c] = 0.f; vB[c] = 0.f; }

        #pragma unroll
        for (int d = 0; d < 7; ++d) {
            const int r = 2 * Rl + d;
            const int e = (r >> 1) & 1;
            const float* base = bufc + r * ROWF;
            float4 f0 = *(const float4*)(base + (((s0    ) ^ e) << 2));
            float4 f1 = *(const float4*)(base + (((s0 + 1) ^ e) << 2));
            float4 f2 = *(const float4*)(base + (((s0 + 2) ^ e) << 2));
            float v12 = base[((s0 + 3) ^ e) << 2];
            float v[13] = {f0.x, f0.y, f0.z, f0.w,
                           f1.x, f1.y, f1.z, f1.w,
                           f2.x, f2.y, f2.z, f2.w, v12};
            #pragma unroll
            for (int c = 0; c < 13; ++c) vB[c] += h1c[d] * v[c];
            if (d >= 2) {
                #pragma unroll
                for (int c = 0; c < 13; ++c) vA[c] += h0c[d - 2] * v[c];
            }
        }

        __builtin_amdgcn_sched_barrier(0);
        __builtin_amdgcn_s_barrier();              // all waves done reading
        __builtin_amdgcn_sched_barrier(0);
        if (t + 2 < YT) STAGE(t + 2, t & 1);       // refill freed buffer
        __builtin_amdgcn_sched_barrier(0);         // keep loads before stores

        // horizontal filters + stores (register-only; overlaps next loads)
        float LL[4], LH[4], HL[4], HH[4];
        #pragma unroll
        for (int u = 0; u < 4; ++u) {
            const float* a = vA + 2 * u;
            const float* b = vB + 2 * u;
            LL[u] = h0c[0]*a[2] + h0c[1]*a[3] + h0c[2]*a[4]
                  + h0c[3]*a[5] + h0c[4]*a[6];
            HL[u] = h1c[0]*a[0] + h1c[1]*a[1] + h1c[2]*a[2] + h1c[3]*a[3]
                  + h1c[4]*a[4] + h1c[5]*a[5] + h1c[6]*a[6];
            LH[u] = h0c[0]*b[2] + h0c[1]*b[3] + h0c[2]*b[4]
                  + h0c[3]*b[5] + h0c[4]*b[6];
            HH[u] = h1c[0]*b[0] + h1c[1]*b[1] + h1c[2]*b[2] + h1c[3]*b[3]
                  + h1c[4]*b[4] + h1c[5]*b[5] + h1c[6]*b[6];
        }
        const int R  = R0b + t * BROWS + Rl;
        const int J0 = J0b + (tid & 15) * 4;
        const size_t off = (size_t)R * WOUT + J0;
        *(float4*)(o + 0*SB + off) = make_float4(LL[0], LL[1], LL[2], LL[3]);
        *(float4*)(o + 1*SB + off) = make_float4(LH[0], LH[1], LH[2], LH[3]);
        *(float4*)(o + 2*SB + off) = make_float4(HL[0], HL[1], HL[2], HL[3]);
        *(float4*)(o + 3*SB + off) = make_float4(HH[0], HH[1], HH[2], HH[3]);
    }
}

extern "C" void kernel_launch(void* const* d_in, const int* in_sizes, int n_in,
                              void* d_out, int out_size, void* d_ws, size_t ws_size,
                              hipStream_t stream) {
    const float* x = (const float*)d_in[0];
    float* out = (float*)d_out;
    dim3 grid(WOUT / BCOLS, HOUT / (BROWS * YT), NIMG);   // 8 x 4 x 24 = 768
    wfb_kernel<<<grid, dim3(256), 0, stream>>>(x, out);
}